// Round 2
// baseline (1422.349 us; speedup 1.0000x reference)
//
#include <hip/hip_runtime.h>
#include <hip/hip_bf16.h>

// FAPBlur: foveated adaptive gaussian blur.
// out(p) = sepconv(x, gauss(sigma_q))(p) where q = bin(p) depends only on
// distance from p to nearest fixation (monotone) -> integer d^2 thresholds.

#define TS 64
#define RMAX 34
#define XB 132                 // TS + 2*RMAX
#define XBUF_N (XB * XB + 8)   // +8 tail pad (finite values, zero-weight taps)
#define HROWS 136              // 132 + 4 window lookahead

// ---------------- kernel 0: thresholds + gaussian weights ----------------
__global__ void precompute_kernel(float* __restrict__ gw, int* __restrict__ thr) {
    int t = threadIdx.x;
    if (t >= 1 && t < 16) {
        // minimal integer d2 with sigma_px(d2) > 0.75*t  (weakly monotone)
        float edge = 0.75f * (float)t;
        int lo = 0, hi = 2093059;   // > 2*1023^2, predicate true at hi
        while (lo < hi) {
            int mid = (lo + hi) >> 1;
            float d  = sqrtf((float)mid);      // matches jnp.sqrt on exact ints
            float dm = d * 0.07f;              // PIXEL_MM
            float a  = 1.5f * (dm - 18.2f);    // ALPHA*(d_mm - MU)
            double p = 1.0 / (1.0 + exp((double)(-a)));   // accurate sigmoid
            float sm = 0.84f * (float)p;       // BETA
            float v  = fminf(fmaxf(sm / 0.07f, 0.0f), 12.0f);
            if (v > edge) hi = mid; else lo = mid + 1;
        }
        thr[t] = lo;
    }
    if (t >= 32 && t < 48) {
        int q = t - 32;
        double s = 0.75 * ((double)q + 0.5);   // bin-center sigma (exact dyadic)
        int R = (9 * q + 4) >> 2;              // == int(3*s)
        int ksz = 2 * R + 1;
        double sum = 0.0;
        for (int j = 0; j < ksz; j++) {
            double ax = (double)(j - R);
            sum += exp(-0.5 * (ax / s) * (ax / s));
        }
        for (int j = 0; j < ksz; j++) {
            double ax = (double)(j - R);
            gw[q * 69 + j] = (float)(exp(-0.5 * (ax / s) * (ax / s)) / sum);
        }
    }
}

// ---------------- kernel 1: per-pixel bin (pure integer) ----------------
__global__ __launch_bounds__(256) void bins_kernel(const int* __restrict__ fix,
                                                   const int* __restrict__ thr,
                                                   unsigned char* __restrict__ binsOut) {
    int blk = blockIdx.x;          // 8 * 1024 blocks
    int b   = blk >> 10;
    int row = blk & 1023;
    const int* f = fix + b * 6;    // [F=3][2] (y,x)
    int fy0 = f[0], fx0 = f[1], fy1 = f[2], fx1 = f[3], fy2 = f[4], fx2 = f[5];
    int dy0 = (row - fy0) * (row - fy0);
    int dy1 = (row - fy1) * (row - fy1);
    int dy2 = (row - fy2) * (row - fy2);
    int T[16];
#pragma unroll
    for (int q = 1; q < 16; q++) T[q] = thr[q];   // uniform -> s_loads
    int xx = threadIdx.x << 2;
    uchar4 r4;
    unsigned char* pr = (unsigned char*)&r4;
#pragma unroll
    for (int k = 0; k < 4; k++) {
        int xk = xx + k;
        int a0 = dy0 + (xk - fx0) * (xk - fx0);
        int a1 = dy1 + (xk - fx1) * (xk - fx1);
        int a2 = dy2 + (xk - fx2) * (xk - fx2);
        int d2 = min(a0, min(a1, a2));
        int bin = 0;
#pragma unroll
        for (int q = 1; q < 16; q++) bin += (d2 >= T[q]) ? 1 : 0;
        pr[k] = (unsigned char)bin;
    }
    *(uchar4*)&binsOut[((size_t)b << 20) + ((size_t)row << 10) + xx] = r4;
}

// ---------------- kernel 2: tiled separable blur, per-present-bin ----------------
__global__ __launch_bounds__(512) void tile_kernel(const float* __restrict__ x,
                                                   const unsigned char* __restrict__ bins,
                                                   const float* __restrict__ gw,
                                                   float* __restrict__ out) {
    __shared__ __align__(16) float xbuf[XBUF_N];      // 69,728 B
    __shared__ __align__(16) float hbuf[HROWS * 64];  // 34,816 B
    __shared__ __align__(16) float wv[80];            // vertical weights (zero-padded)
    __shared__ __align__(16) float wh[80];            // horiz weights, lead-shifted for b128 align
    __shared__ unsigned int mask_sh;

    int blk = blockIdx.x;
    int tx = blk & 15, ty = (blk >> 4) & 15;
    int bc = blk >> 8;                 // 0..23 (b*3 + c)
    const size_t plane = (size_t)bc << 20;
    const float* xp = x + plane;
    float* op = out + plane;
    const unsigned char* bp = bins + ((size_t)(bc / 3) << 20);
    int x0 = tx << 6, y0 = ty << 6;
    int tid = threadIdx.x;

    if (tid == 0) mask_sh = 0;
    for (int i = tid; i < HROWS * 64; i += 512) hbuf[i] = 0.f;  // finite pad rows
    __syncthreads();   // mask_sh init visible BEFORE any atomicOr (race fix)

    // per-thread output pixels: col c, rows rgp + it*32 + k (it<2, k<4)
    int c = tid & 63;
    int rgp = (tid >> 6) << 2;  // 0,4,..,28
    unsigned char myb[8];
    unsigned int m = 0;
#pragma unroll
    for (int i = 0; i < 8; i++) {
        int row = rgp + ((i >> 2) << 5) + (i & 3);
        myb[i] = bp[((size_t)(y0 + row) << 10) + x0 + c];
        m |= 1u << myb[i];
    }
    atomicOr(&mask_sh, m);

    // stage zero-padded input tile
    for (int idx = tid; idx < XBUF_N; idx += 512) {
        int r = idx / XB, c2 = idx - r * XB;
        int gy = y0 - RMAX + r, gx = x0 - RMAX + c2;
        float v = 0.f;
        if ((unsigned)gy < 1024u && (unsigned)gx < 1024u) v = xp[((size_t)gy << 10) + gx];
        xbuf[idx] = v;
    }
    __syncthreads();

    unsigned int mask = mask_sh;
    float accOut[8];
#pragma unroll
    for (int i = 0; i < 8; i++) accOut[i] = 0.f;

    while (mask) {
        int q = __ffs(mask) - 1;
        mask &= mask - 1;
        int R = (9 * q + 4) >> 2;
        int ks = 2 * R + 1;
        int off = RMAX - R;
        int lead = off & 3;
        int Abase = off - lead;
        int ksEh = (lead + ks + 3) & ~3;   // <= 72
        int ksEv = (ks + 3) & ~3;          // <= 72

        if (tid < 80) {
            wv[tid] = (tid < ks) ? gw[q * 69 + tid] : 0.f;
        } else if (tid >= 128 && tid < 208) {
            int j = tid - 128;
            wh[j] = (j >= lead && j < lead + ks) ? gw[q * 69 + (j - lead)] : 0.f;
        }
        __syncthreads();

        // horizontal blur: rows [0, 64+2R) of hbuf, 4 cols/thread, sliding float4 window
        int nrows = TS + 2 * R;
        int cg = (tid & 15) << 2;
        int hr0 = tid >> 4;  // 0..31
        for (int hr = hr0; hr < nrows; hr += 32) {
            const float* xrow = &xbuf[(off + hr) * XB + Abase + cg];
            float4 q0 = *(const float4*)xrow;
            float a0 = 0.f, a1 = 0.f, a2 = 0.f, a3 = 0.f;
            for (int jb = 0; jb < ksEh; jb += 4) {
                float4 wq = *(const float4*)&wh[jb];
                float4 q1 = *(const float4*)(xrow + jb + 4);
                a0 += wq.x * q0.x + wq.y * q0.y + wq.z * q0.z + wq.w * q0.w;
                a1 += wq.x * q0.y + wq.y * q0.z + wq.z * q0.w + wq.w * q1.x;
                a2 += wq.x * q0.z + wq.y * q0.w + wq.z * q1.x + wq.w * q1.y;
                a3 += wq.x * q0.w + wq.y * q1.x + wq.z * q1.y + wq.w * q1.z;
                q0 = q1;
            }
            *(float4*)&hbuf[(hr << 6) + cg] = make_float4(a0, a1, a2, a3);
        }
        __syncthreads();

        // vertical blur: 4 adjacent rows/thread, scalar sliding window (4x reuse)
#pragma unroll
        for (int it = 0; it < 2; it++) {
            int r0 = rgp + (it << 5);
            float w0 = hbuf[((r0 + 0) << 6) + c], w1 = hbuf[((r0 + 1) << 6) + c];
            float w2 = hbuf[((r0 + 2) << 6) + c], w3 = hbuf[((r0 + 3) << 6) + c];
            float a0 = 0.f, a1 = 0.f, a2 = 0.f, a3 = 0.f;
            for (int jb = 0; jb < ksEv; jb += 4) {
                float4 wq = *(const float4*)&wv[jb];
                float n0 = hbuf[((r0 + jb + 4) << 6) + c];
                float n1 = hbuf[((r0 + jb + 5) << 6) + c];
                float n2 = hbuf[((r0 + jb + 6) << 6) + c];
                float n3 = hbuf[((r0 + jb + 7) << 6) + c];
                a0 += wq.x * w0 + wq.y * w1 + wq.z * w2 + wq.w * w3;
                a1 += wq.x * w1 + wq.y * w2 + wq.z * w3 + wq.w * n0;
                a2 += wq.x * w2 + wq.y * w3 + wq.z * n0 + wq.w * n1;
                a3 += wq.x * w3 + wq.y * n0 + wq.z * n1 + wq.w * n2;
                w0 = n0; w1 = n1; w2 = n2; w3 = n3;
            }
            if (myb[it * 4 + 0] == q) accOut[it * 4 + 0] = a0;
            if (myb[it * 4 + 1] == q) accOut[it * 4 + 1] = a1;
            if (myb[it * 4 + 2] == q) accOut[it * 4 + 2] = a2;
            if (myb[it * 4 + 3] == q) accOut[it * 4 + 3] = a3;
        }
        __syncthreads();
    }

#pragma unroll
    for (int i = 0; i < 8; i++) {
        int row = rgp + ((i >> 2) << 5) + (i & 3);
        op[((size_t)(y0 + row) << 10) + x0 + c] = accOut[i];
    }
}

extern "C" void kernel_launch(void* const* d_in, const int* in_sizes, int n_in,
                              void* d_out, int out_size, void* d_ws, size_t ws_size,
                              hipStream_t stream) {
    const float* x = (const float*)d_in[0];
    const int* fix = (const int*)d_in[1];
    float* out = (float*)d_out;

    float* gw = (float*)d_ws;                              // 16*69 floats
    int* thr = (int*)((char*)d_ws + 4608);                 // 16 ints
    unsigned char* bins = (unsigned char*)d_ws + 8192;     // 8*1024*1024 bytes

    hipLaunchKernelGGL(precompute_kernel, dim3(1), dim3(64), 0, stream, gw, thr);
    hipLaunchKernelGGL(bins_kernel, dim3(8 * 1024), dim3(256), 0, stream, fix, thr, bins);
    hipLaunchKernelGGL(tile_kernel, dim3(24 * 16 * 16), dim3(512), 0, stream, x, bins, gw, out);
}

// Round 3
// 849.465 us; speedup vs baseline: 1.6744x; 1.6744x over previous
//
#include <hip/hip_runtime.h>
#include <hip/hip_bf16.h>

// FAPBlur: foveated adaptive gaussian blur.
// bin(p) from integer d^2 thresholds (monotone map); per-tile loop over
// present bins: hblur (global->LDS hbuf) then vblur (LDS->regs->global).
// R3: no xbuf (global-direct hblur), scalar weight loads, hbuf stride 68.

#define HSTRIDE 68             // 68 mod 32 = 4 -> spread bank quads
#define HROWS 136

// ---------------- kernel 0: thresholds + shifted gaussian weights ----------------
__global__ void precompute_kernel(float* __restrict__ wtab, int* __restrict__ thr) {
    int t = threadIdx.x;
    if (t >= 1 && t < 16) {
        // minimal integer d2 with sigma_px(d2) > 0.75*t  (weakly monotone)
        float edge = 0.75f * (float)t;
        int lo = 0, hi = 2093059;   // > 2*1023^2, predicate true at hi
        while (lo < hi) {
            int mid = (lo + hi) >> 1;
            float d  = sqrtf((float)mid);
            float dm = d * 0.07f;              // PIXEL_MM
            float a  = 1.5f * (dm - 18.2f);    // ALPHA*(d_mm - MU)
            double p = 1.0 / (1.0 + exp((double)(-a)));
            float sm = 0.84f * (float)p;       // BETA
            float v  = fminf(fmaxf(sm / 0.07f, 0.0f), 12.0f);
            if (v > edge) hi = mid; else lo = mid + 1;
        }
        thr[t] = lo;
    }
    if (t >= 32 && t < 48) {
        int q = t - 32;
        double s = 0.75 * ((double)q + 0.5);   // bin-center sigma
        int R = (9 * q + 4) >> 2;              // == int(3*s)
        int ksz = 2 * R + 1;
        double sum = 0.0;
        for (int j = 0; j < ksz; j++) {
            double ax = (double)(j - R);
            sum += exp(-0.5 * (ax / s) * (ax / s));
        }
        // 4 pre-shifted, zero-padded copies: wtab[(q*4+sh)*72 + jj] = w[jj-sh]
        for (int sh = 0; sh < 4; sh++) {
            for (int jj = 0; jj < 72; jj++) {
                int j = jj - sh;
                float w = 0.f;
                if (j >= 0 && j < ksz) {
                    double ax = (double)(j - R);
                    w = (float)(exp(-0.5 * (ax / s) * (ax / s)) / sum);
                }
                wtab[(q * 4 + sh) * 72 + jj] = w;
            }
        }
    }
}

// ---------------- kernel 1: per-pixel bin (pure integer) ----------------
__global__ __launch_bounds__(256) void bins_kernel(const int* __restrict__ fix,
                                                   const int* __restrict__ thr,
                                                   unsigned char* __restrict__ binsOut) {
    int blk = blockIdx.x;          // 8 * 1024 blocks
    int b   = blk >> 10;
    int row = blk & 1023;
    const int* f = fix + b * 6;    // [F=3][2] (y,x)
    int fy0 = f[0], fx0 = f[1], fy1 = f[2], fx1 = f[3], fy2 = f[4], fx2 = f[5];
    int dy0 = (row - fy0) * (row - fy0);
    int dy1 = (row - fy1) * (row - fy1);
    int dy2 = (row - fy2) * (row - fy2);
    int T[16];
#pragma unroll
    for (int q = 1; q < 16; q++) T[q] = thr[q];
    int xx = threadIdx.x << 2;
    uchar4 r4;
    unsigned char* pr = (unsigned char*)&r4;
#pragma unroll
    for (int k = 0; k < 4; k++) {
        int xk = xx + k;
        int a0 = dy0 + (xk - fx0) * (xk - fx0);
        int a1 = dy1 + (xk - fx1) * (xk - fx1);
        int a2 = dy2 + (xk - fx2) * (xk - fx2);
        int d2 = min(a0, min(a1, a2));
        int bin = 0;
#pragma unroll
        for (int q = 1; q < 16; q++) bin += (d2 >= T[q]) ? 1 : 0;
        pr[k] = (unsigned char)bin;
    }
    *(uchar4*)&binsOut[((size_t)b << 20) + ((size_t)row << 10) + xx] = r4;
}

// ---------------- kernel 2: tiled separable blur, per-present-bin ----------------
__global__ __launch_bounds__(512, 6) void tile_kernel(const float* __restrict__ x,
                                                      const unsigned char* __restrict__ bins,
                                                      const float* __restrict__ wtab,
                                                      float* __restrict__ out) {
    __shared__ __align__(16) float hbuf[HROWS * HSTRIDE];  // 36,992 B
    __shared__ unsigned int mask_sh;

    int blk = blockIdx.x;
    int tx = blk & 15, ty = (blk >> 4) & 15;
    int bc = blk >> 8;                 // 0..23 (b*3 + c)
    const size_t plane = (size_t)bc << 20;
    const float* xp = x + plane;
    float* op = out + plane;
    const unsigned char* bp = bins + ((size_t)(bc / 3) << 20);
    int x0 = tx << 6, y0 = ty << 6;
    int tid = threadIdx.x;
    bool edgeX = (tx == 0) || (tx == 15);

    if (tid == 0) mask_sh = 0;
    for (int i = tid; i < HROWS * HSTRIDE; i += 512) hbuf[i] = 0.f;  // finite pad
    __syncthreads();

    // per-thread output pixels: col c, rows rgp+{0..3} and rgp+32+{0..3}
    int c = tid & 63;
    int rgp = (tid >> 6) << 2;
    unsigned char myb[8];
    unsigned int m = 0;
#pragma unroll
    for (int i = 0; i < 8; i++) {
        int row = rgp + ((i >> 2) << 5) + (i & 3);
        myb[i] = bp[((size_t)(y0 + row) << 10) + x0 + c];
        m |= 1u << myb[i];
    }
    atomicOr(&mask_sh, m);
    __syncthreads();

    unsigned int mask = mask_sh;
    float accOut[8];
#pragma unroll
    for (int i = 0; i < 8; i++) accOut[i] = 0.f;

    int ht  = tid >> 3;          // 0..63: hblur row within 64-row stripe
    int hc8 = (tid & 7) << 3;    // 0,8,...,56: 8-col group

    while (mask) {
        int q = __ffs(mask) - 1;
        mask &= mask - 1;
        q = __builtin_amdgcn_readfirstlane(q);   // provably uniform -> SGPR math
        int R = (9 * q + 4) >> 2;
        int ks = 2 * R + 1;
        int lead = (-R) & 3;
        int ksEh = (lead + ks + 3) & ~3;   // <= 72
        int ksEv = (ks + 3) & ~3;          // <= 72
        int nrows = 64 + 2 * R;
        const float* wh = wtab + (size_t)(q * 4 + lead) * 72;  // scalar loads
        const float* wv = wtab + (size_t)(q * 4) * 72;

        // ---- horizontal: hbuf[hr][c'] = sum_j w[j] * x[y0-R+hr][x0+c'-R+j]
        for (int hr = ht; hr < nrows; hr += 64) {
            int gy = y0 - R + hr;
            float* hd = &hbuf[hr * HSTRIDE + hc8];
            if ((unsigned)gy < 1024u) {
                const float* xr = xp + ((size_t)gy << 10);
                int A = x0 + hc8 - R - lead;   // 4-aligned
                float a0 = 0.f, a1 = 0.f, a2 = 0.f, a3 = 0.f;
                float a4 = 0.f, a5 = 0.f, a6 = 0.f, a7 = 0.f;
                if (!edgeX) {
                    float4 q0 = *(const float4*)(xr + A);
                    float4 q1 = *(const float4*)(xr + A + 4);
                    for (int jb = 0; jb < ksEh; jb += 4) {
                        float4 wq = *(const float4*)(wh + jb);
                        float4 q2 = *(const float4*)(xr + A + jb + 8);
                        a0 += wq.x * q0.x + wq.y * q0.y + wq.z * q0.z + wq.w * q0.w;
                        a1 += wq.x * q0.y + wq.y * q0.z + wq.z * q0.w + wq.w * q1.x;
                        a2 += wq.x * q0.z + wq.y * q0.w + wq.z * q1.x + wq.w * q1.y;
                        a3 += wq.x * q0.w + wq.y * q1.x + wq.z * q1.y + wq.w * q1.z;
                        a4 += wq.x * q1.x + wq.y * q1.y + wq.z * q1.z + wq.w * q1.w;
                        a5 += wq.x * q1.y + wq.y * q1.z + wq.z * q1.w + wq.w * q2.x;
                        a6 += wq.x * q1.z + wq.y * q1.w + wq.z * q2.x + wq.w * q2.y;
                        a7 += wq.x * q1.w + wq.y * q2.x + wq.z * q2.y + wq.w * q2.z;
                        q0 = q1; q1 = q2;
                    }
                } else {
                    // edge tiles: per-float4 uniform validity (A,jb mult of 4,
                    // bounds mult of 4 -> each float4 fully in or fully out)
                    auto g4 = [&](int idx) -> float4 {
                        bool v = (unsigned)idx < 1021u;   // 0 <= idx <= 1020
                        const float* p = xr + (v ? idx : 0);
                        float4 r = *(const float4*)p;
                        if (!v) { r.x = 0.f; r.y = 0.f; r.z = 0.f; r.w = 0.f; }
                        return r;
                    };
                    float4 q0 = g4(A);
                    float4 q1 = g4(A + 4);
                    for (int jb = 0; jb < ksEh; jb += 4) {
                        float4 wq = *(const float4*)(wh + jb);
                        float4 q2 = g4(A + jb + 8);
                        a0 += wq.x * q0.x + wq.y * q0.y + wq.z * q0.z + wq.w * q0.w;
                        a1 += wq.x * q0.y + wq.y * q0.z + wq.z * q0.w + wq.w * q1.x;
                        a2 += wq.x * q0.z + wq.y * q0.w + wq.z * q1.x + wq.w * q1.y;
                        a3 += wq.x * q0.w + wq.y * q1.x + wq.z * q1.y + wq.w * q1.z;
                        a4 += wq.x * q1.x + wq.y * q1.y + wq.z * q1.z + wq.w * q1.w;
                        a5 += wq.x * q1.y + wq.y * q1.z + wq.z * q1.w + wq.w * q2.x;
                        a6 += wq.x * q1.z + wq.y * q1.w + wq.z * q2.x + wq.w * q2.y;
                        a7 += wq.x * q1.w + wq.y * q2.x + wq.z * q2.y + wq.w * q2.z;
                        q0 = q1; q1 = q2;
                    }
                }
                *(float4*)hd       = make_float4(a0, a1, a2, a3);
                *(float4*)(hd + 4) = make_float4(a4, a5, a6, a7);
            } else {
                *(float4*)hd       = make_float4(0.f, 0.f, 0.f, 0.f);
                *(float4*)(hd + 4) = make_float4(0.f, 0.f, 0.f, 0.f);
            }
        }
        __syncthreads();

        // ---- vertical: out[r][c] = sum_j wv[j] * hbuf[r+j][c]
#pragma unroll
        for (int it = 0; it < 2; it++) {
            int r0 = rgp + (it << 5);
            float w0 = hbuf[(r0 + 0) * HSTRIDE + c], w1 = hbuf[(r0 + 1) * HSTRIDE + c];
            float w2 = hbuf[(r0 + 2) * HSTRIDE + c], w3 = hbuf[(r0 + 3) * HSTRIDE + c];
            float a0 = 0.f, a1 = 0.f, a2 = 0.f, a3 = 0.f;
            for (int jb = 0; jb < ksEv; jb += 4) {
                float4 wq = *(const float4*)(wv + jb);
                float n0 = hbuf[(r0 + jb + 4) * HSTRIDE + c];
                float n1 = hbuf[(r0 + jb + 5) * HSTRIDE + c];
                float n2 = hbuf[(r0 + jb + 6) * HSTRIDE + c];
                float n3 = hbuf[(r0 + jb + 7) * HSTRIDE + c];
                a0 += wq.x * w0 + wq.y * w1 + wq.z * w2 + wq.w * w3;
                a1 += wq.x * w1 + wq.y * w2 + wq.z * w3 + wq.w * n0;
                a2 += wq.x * w2 + wq.y * w3 + wq.z * n0 + wq.w * n1;
                a3 += wq.x * w3 + wq.y * n0 + wq.z * n1 + wq.w * n2;
                w0 = n0; w1 = n1; w2 = n2; w3 = n3;
            }
            if (myb[it * 4 + 0] == q) accOut[it * 4 + 0] = a0;
            if (myb[it * 4 + 1] == q) accOut[it * 4 + 1] = a1;
            if (myb[it * 4 + 2] == q) accOut[it * 4 + 2] = a2;
            if (myb[it * 4 + 3] == q) accOut[it * 4 + 3] = a3;
        }
        if (mask) __syncthreads();   // protect hbuf before next bin's hblur
    }

#pragma unroll
    for (int i = 0; i < 8; i++) {
        int row = rgp + ((i >> 2) << 5) + (i & 3);
        op[((size_t)(y0 + row) << 10) + x0 + c] = accOut[i];
    }
}

extern "C" void kernel_launch(void* const* d_in, const int* in_sizes, int n_in,
                              void* d_out, int out_size, void* d_ws, size_t ws_size,
                              hipStream_t stream) {
    const float* x = (const float*)d_in[0];
    const int* fix = (const int*)d_in[1];
    float* out = (float*)d_out;

    float* wtab = (float*)d_ws;                            // 16*4*72 floats = 18,432 B
    int* thr = (int*)((char*)d_ws + 18432);                // 16 ints
    unsigned char* bins = (unsigned char*)d_ws + 20480;    // 8 MB

    hipLaunchKernelGGL(precompute_kernel, dim3(1), dim3(64), 0, stream, wtab, thr);
    hipLaunchKernelGGL(bins_kernel, dim3(8 * 1024), dim3(256), 0, stream, fix, thr, bins);
    hipLaunchKernelGGL(tile_kernel, dim3(24 * 16 * 16), dim3(512), 0, stream, x, bins, wtab, out);
}